// Round 11
// baseline (148.510 us; speedup 1.0000x reference)
//
#include <hip/hip_runtime.h>

typedef __bf16 bf16x8 __attribute__((ext_vector_type(8)));
typedef float f32x4 __attribute__((ext_vector_type(4)));
typedef float f32x16 __attribute__((ext_vector_type(16)));
typedef unsigned int u32;
typedef u32 u32x4 __attribute__((ext_vector_type(4)));

constexpr int Bc = 2, Sc = 2048, Hc = 16, Dc = 64;
constexpr int QBLK = 64, KVBLK = 64;
constexpr int NT = Sc / QBLK;          // 32 q-tiles
constexpr int ROWSTR = 3 * Hc * Dc;    // 3072 floats between consecutive s
constexpr float QSCALE = 0.125f * 1.4426950408889634f;  // 1/sqrt(D) * log2e

// MFMA f32_32x32x16_bf16 layouts (learn_hip m74/m101):
//   A[m][k]: lane l, elem j -> m = l&31, k = 8*(l>>5)+j
//   B[k][n]: lane l, elem j -> k = 8*(l>>5)+j, n = l&31
//   C/D[m][n]: lane l, reg r -> n = l&31, m = (r&3) + 8*(r>>2) + 4*(l>>5)
// Swapped-QK^T: S^T[kv][q] = mfma32(K, Q^T): lane holds 32 kv values of ONE
// q row (partner l^32 has the other 32). PV: O^T = mfma32(V^T, P^T).

template <int CTRL>
static __device__ __forceinline__ float dppf(float x) {
  int xi = __builtin_bit_cast(int, x);
  return __builtin_bit_cast(float,
      __builtin_amdgcn_update_dpp(xi, xi, CTRL, 0xF, 0xF, false));
}

static __device__ __forceinline__ u32 pack2(float a, float b) {
  unsigned short x = __builtin_bit_cast(unsigned short, (__bf16)a);
  unsigned short y = __builtin_bit_cast(unsigned short, (__bf16)b);
  return (u32)x | ((u32)y << 16);
}

__global__ __launch_bounds__(128, 4)
void fattn_kernel(const float* __restrict__ qkv, float* __restrict__ out) {
  // One 64-row q-tile per block; long blocks (high x) dispatch first so the
  // backfill scheduler packs the causal imbalance. Blocks sharing a head are
  // ids {bh, bh+32, ...} -> same id%8 -> same XCD -> KV L2 reuse.
  const int raw = blockIdx.x;            // 0..1023
  const int x = NT - 1 - (raw >> 5);     // 31..0
  const int bh = raw & 31;
  const int b = bh >> 4, h = bh & 15;

  const int tid = threadIdx.x;           // 0..127
  const int wave = tid >> 6;             // 0..1
  const int lane = tid & 63;
  const int hh = lane >> 5;              // lane half
  const int q = lane & 31;               // this lane's q column (within 32)

  const int qw = x * QBLK + wave * 32;   // wave 0: rows 0..31, wave 1: 32..63
  const int myq = qw + q;

  const float* qp = qkv + (size_t)b * Sc * ROWSTR + h * Dc;
  const float* kp = qp + Hc * Dc;
  const float* vp = qp + 2 * Hc * Dc;

  __shared__ __align__(16) char k_s[KVBLK * Dc * 2];   // [kv][d] bf16, XOR-swz
  __shared__ __align__(16) char v_s[Dc * KVBLK * 2];   // V^T [d][kv] bf16, XOR-swz

  // ---- Q fragments (B-operand): lane l supplies Q[myq][16c+8hh+j] ----
  bf16x8 qf[4];
#pragma unroll
  for (int c = 0; c < 4; ++c) {
    const float* qr = qp + (size_t)myq * ROWSTR + 16 * c + 8 * hh;
    f32x4 a0 = *(const f32x4*)qr;
    f32x4 a1 = *(const f32x4*)(qr + 4);
    bf16x8 qa;
#pragma unroll
    for (int j = 0; j < 4; ++j) {
      qa[j] = (__bf16)(a0[j] * QSCALE); qa[j + 4] = (__bf16)(a1[j] * QSCALE);
    }
    qf[c] = qa;
  }

  f32x16 o0, o1;
#pragma unroll
  for (int i = 0; i < 16; ++i) { o0[i] = 0.f; o1[i] = 0.f; }
  float mreg = -1e30f, lsum = 0.f;

  const int swq = (q & 7) << 4;   // XOR swizzle for rows q and q+32 (same &7)

  for (int t = 0; t <= x; ++t) {
    const int kv0 = t * KVBLK;

    // ---- staging: 128 threads cover K+V tile (R6-verified layouts) ----
#pragma unroll
    for (int it = 0; it < 4; ++it) {
      const int u = tid + it * 128, r = u >> 3, g = u & 7;
      const float* ks = kp + (size_t)(kv0 + r) * ROWSTR + g * 8;
      const float* vs = vp + (size_t)(kv0 + r) * ROWSTR + g * 8;
      f32x4 k0 = *(const f32x4*)ks;
      f32x4 k1 = *(const f32x4*)(ks + 4);
      f32x4 v0 = *(const f32x4*)vs;
      f32x4 v1 = *(const f32x4*)(vs + 4);
      bf16x8 kb;
#pragma unroll
      for (int j = 0; j < 4; ++j) { kb[j] = (__bf16)k0[j]; kb[j + 4] = (__bf16)k1[j]; }
      *(bf16x8*)(k_s + ((r * 128 + g * 16) ^ ((r & 7) << 4))) = kb;

      // V^T: pair kv rows (r, r^1) via DPP row_ror:8 (lane^8 within 16-row);
      // even r keeps d 0..3 of its octet, odd r keeps d 4..7; rotate store
      // order by g so simultaneous stores spread d&7 across banks.
      const int odd = r & 1;
      f32x4 tmp = odd ? v0 : v1;
      f32x4 rcv;
#pragma unroll
      for (int j = 0; j < 4; ++j) rcv[j] = dppf<0x128>(tmp[j]);
      const int kvb2 = (r & ~1) * 2;
#pragma unroll
      for (int s = 0; s < 4; ++s) {
        const int dj = (s + g) & 3;
        const float lo = odd ? rcv[dj] : v0[dj];
        const float hi = odd ? v1[dj] : rcv[dj];
        const int d = 8 * g + 4 * odd + dj;
        *(u32*)(v_s + ((d * 128 + kvb2) ^ ((d & 7) << 4))) = pack2(lo, hi);
      }
    }
    __syncthreads();

    // ---- QK^T (swapped): S^T = K * Q^T ----
    f32x16 p0, p1;
#pragma unroll
    for (int i = 0; i < 16; ++i) { p0[i] = 0.f; p1[i] = 0.f; }
    __builtin_amdgcn_s_setprio(1);
#pragma unroll
    for (int c = 0; c < 4; ++c) {
      const int off = (16 * c + 8 * hh) * 2;
      bf16x8 kf0 = *(const bf16x8*)(k_s + ((q * 128 + off) ^ swq));
      bf16x8 kf1 = *(const bf16x8*)(k_s + (((32 + q) * 128 + off) ^ swq));
      p0 = __builtin_amdgcn_mfma_f32_32x32x16_bf16(kf0, qf[c], p0, 0, 0, 0);
      p1 = __builtin_amdgcn_mfma_f32_32x32x16_bf16(kf1, qf[c], p1, 0, 0, 0);
    }
    __builtin_amdgcn_s_setprio(0);

    // ---- causal mask (diagonal tile only) ----
    if (t == x) {
#pragma unroll
      for (int r = 0; r < 16; ++r) {
        const int kvl = (r & 3) + 8 * (r >> 2) + 4 * hh;
        if (kv0 + kvl > myq) p0[r] = -1e30f;
        if (kv0 + 32 + kvl > myq) p1[r] = -1e30f;
      }
    }

    // ---- softmax (per-lane in-register; one half-exchange) ----
    float tr[16];
#pragma unroll
    for (int i = 0; i < 16; ++i) tr[i] = fmaxf(p0[i], p1[i]);
#pragma unroll
    for (int s = 8; s > 0; s >>= 1)
#pragma unroll
      for (int i = 0; i < 8; ++i)
        if (i < s) tr[i] = fmaxf(tr[i], tr[i + s]);
    float pm = fmaxf(tr[0], __shfl_xor(tr[0], 32, 64));

    if (__any(pm > mreg + 8.0f)) {
      float mn = fmaxf(mreg, pm);
      float scl = __builtin_exp2f(mreg - mn);
      mreg = mn;
      lsum *= scl;
      o0 *= scl;
      o1 *= scl;
    }

    float s0 = 0.f, s1 = 0.f, s2 = 0.f, s3 = 0.f;
#pragma unroll
    for (int i = 0; i < 16; ++i) {
      p0[i] = __builtin_exp2f(p0[i] - mreg);
      p1[i] = __builtin_exp2f(p1[i] - mreg);
    }
#pragma unroll
    for (int i = 0; i < 4; ++i) {
      s0 += p0[4 * i + 0] + p1[4 * i + 0];
      s1 += p0[4 * i + 1] + p1[4 * i + 1];
      s2 += p0[4 * i + 2] + p1[4 * i + 2];
      s3 += p0[4 * i + 3] + p1[4 * i + 3];
    }
    lsum += (s0 + s1) + (s2 + s3);

    // ---- build P^T B-frags from registers (pack + half-exchange) ----
    bf16x8 pb[4];
#pragma unroll
    for (int c = 0; c < 4; ++c) {
      const int m0 = 2 * (c & 1);
      const f32x16& P = (c < 2) ? p0 : p1;
      u32 A0 = pack2(P[4 * m0 + 0], P[4 * m0 + 1]);
      u32 A1 = pack2(P[4 * m0 + 2], P[4 * m0 + 3]);
      u32 B0 = pack2(P[4 * m0 + 4], P[4 * m0 + 5]);
      u32 B1 = pack2(P[4 * m0 + 6], P[4 * m0 + 7]);
      u32 snd0 = hh ? A0 : B0;
      u32 snd1 = hh ? A1 : B1;
      u32 rcv0 = (u32)__shfl_xor((int)snd0, 32, 64);
      u32 rcv1 = (u32)__shfl_xor((int)snd1, 32, 64);
      u32x4 f;
      f[0] = hh ? rcv0 : A0;
      f[1] = hh ? rcv1 : A1;
      f[2] = hh ? B0 : rcv0;
      f[3] = hh ? B1 : rcv1;
      pb[c] = __builtin_bit_cast(bf16x8, f);
    }

    // ---- PV: O^T += V^T * P^T ----
    __builtin_amdgcn_s_setprio(1);
#pragma unroll
    for (int c = 0; c < 4; ++c) {
      const int off = (16 * c + 8 * hh) * 2;
      bf16x8 vf0 = *(const bf16x8*)(v_s + ((q * 128 + off) ^ swq));
      bf16x8 vf1 = *(const bf16x8*)(v_s + (((32 + q) * 128 + off) ^ swq));
      o0 = __builtin_amdgcn_mfma_f32_32x32x16_bf16(vf0, pb[c], o0, 0, 0, 0);
      o1 = __builtin_amdgcn_mfma_f32_32x32x16_bf16(vf1, pb[c], o1, 0, 0, 0);
    }
    __builtin_amdgcn_s_setprio(0);

    __syncthreads();
  }

  // ---- epilogue: combine partner lsum, normalize, store O^T ----
  lsum += __shfl_xor(lsum, 32, 64);
  const float inv = 1.0f / lsum;
  float* op = out + ((size_t)(b * Sc + myq) * Hc + h) * Dc;
#pragma unroll
  for (int m = 0; m < 4; ++m) {
    f32x4 w0, w1;
#pragma unroll
    for (int j = 0; j < 4; ++j) {
      w0[j] = o0[4 * m + j] * inv;
      w1[j] = o1[4 * m + j] * inv;
    }
    const int d0 = 8 * m + 4 * hh;
    *(f32x4*)(op + d0) = w0;
    *(f32x4*)(op + 32 + d0) = w1;
  }
}

extern "C" void kernel_launch(void* const* d_in, const int* in_sizes, int n_in,
                              void* d_out, int out_size, void* d_ws, size_t ws_size,
                              hipStream_t stream) {
  const float* qkv = (const float*)d_in[0];
  float* out = (float*)d_out;
  fattn_kernel<<<dim3(NT * Bc * Hc), 128, 0, stream>>>(qkv, out);
}

// Round 14
// 94.606 us; speedup vs baseline: 1.5698x; 1.5698x over previous
//
#include <hip/hip_runtime.h>

typedef __bf16 bf16x8 __attribute__((ext_vector_type(8)));
typedef float f32x4 __attribute__((ext_vector_type(4)));
typedef float f32x16 __attribute__((ext_vector_type(16)));
typedef unsigned int u32;
typedef u32 u32x4 __attribute__((ext_vector_type(4)));
typedef int i32x2 __attribute__((ext_vector_type(2)));

constexpr int Bc = 2, Sc = 2048, Hc = 16, Dc = 64;
constexpr int QBLK = 64, KVBLK = 64;
constexpr int NT = Sc / QBLK;          // 32 q-tiles
constexpr int ROWSTR = 3 * Hc * Dc;    // 3072 floats between consecutive s
constexpr float QSCALE = 0.125f * 1.4426950408889634f;  // 1/sqrt(D) * log2e

// MFMA f32_32x32x16_bf16 layouts (learn_hip m74/m101):
//   A[m][k]: lane l, elem j -> m = l&31, k = 8*(l>>5)+j
//   B[k][n]: lane l, elem j -> k = 8*(l>>5)+j, n = l&31
//   C/D[m][n]: lane l, reg r -> n = l&31, m = (r&3) + 8*(r>>2) + 4*(l>>5)
// Swapped-QK^T: S^T[kv][q] = mfma32(K, Q^T): lane holds 32 kv values of ONE
// q row (partner l^32 has the other 32). PV: O^T = mfma32(V^T, P^T).
//
// permlane32_swap via BUILTIN (guide T12/m240): compiler handles the gfx950
// VALU->permlane wait-state hazard (raw inline asm does not -> R12/R13 fails).
// Result order per T12 recipe: r.x = low-combined word, r.y = high word.

template <int CTRL>
static __device__ __forceinline__ float dppf(float x) {
  int xi = __builtin_bit_cast(int, x);
  return __builtin_bit_cast(float,
      __builtin_amdgcn_update_dpp(xi, xi, CTRL, 0xF, 0xF, false));
}

static __device__ __forceinline__ void pl32swap(u32& lo, u32& hi) {
  i32x2 r = __builtin_amdgcn_permlane32_swap((int)lo, (int)hi, false, false);
  lo = (u32)r.x;
  hi = (u32)r.y;
}
// cross-half reduce helpers: with equal inputs the two outputs are
// [x_lo|x_lo] and [x_hi|x_hi] (order irrelevant); combining both is the
// full cross-half reduce on every lane.
static __device__ __forceinline__ float xhalf_max(float x) {
  u32 a = __builtin_bit_cast(u32, x), b = a;
  pl32swap(a, b);
  return fmaxf(__builtin_bit_cast(float, a), __builtin_bit_cast(float, b));
}
static __device__ __forceinline__ float xhalf_sum(float x) {
  u32 a = __builtin_bit_cast(u32, x), b = a;
  pl32swap(a, b);
  return __builtin_bit_cast(float, a) + __builtin_bit_cast(float, b);
}

static __device__ __forceinline__ u32 pack2(float a, float b) {
  unsigned short x = __builtin_bit_cast(unsigned short, (__bf16)a);
  unsigned short y = __builtin_bit_cast(unsigned short, (__bf16)b);
  return (u32)x | ((u32)y << 16);
}

__global__ __launch_bounds__(256, 2)
void fattn_kernel(const float* __restrict__ qkv, float* __restrict__ out) {
  // XCD-aware bijective swizzle (512 blocks, 512 % 8 == 0)
  const int id = blockIdx.x + blockIdx.y * gridDim.x;   // 0..511
  const int swz = (id & 7) * 64 + (id >> 3);
  const int xlow = swz & 15;            // 0..15
  const int xhigh = NT - 1 - xlow;      // 31..16
  const int bh = swz >> 4;
  const int b = bh >> 4, h = bh & 15;

  const int tid = threadIdx.x;
  const int wave = tid >> 6;            // 0..3
  const int lane = tid & 63;
  const int hh = lane >> 5;             // lane half
  const int q = lane & 31;              // this lane's q column (within 32)

  // waves 0,1 -> H tile rows [0..31],[32..63]; waves 2,3 -> L tile
  const int myx = (wave < 2) ? xhigh : xlow;
  const int qw = myx * QBLK + (wave & 1) * 32;
  const int myq = qw + q;

  const float* qp = qkv + (size_t)b * Sc * ROWSTR + h * Dc;
  const float* kp = qp + Hc * Dc;
  const float* vp = qp + 2 * Hc * Dc;

  __shared__ __align__(16) char k_s[2][KVBLK * Dc * 2];  // [kv][d] bf16, XOR-swz
  __shared__ __align__(16) char v_s[2][Dc * KVBLK * 2];  // V^T [d][kv] bf16, XOR-swz

  // ---- Q fragments (B-operand): lane l supplies Q[myq][16c+8hh+j] ----
  bf16x8 qf[4];
#pragma unroll
  for (int c = 0; c < 4; ++c) {
    const float* qr = qp + (size_t)myq * ROWSTR + 16 * c + 8 * hh;
    f32x4 a0 = *(const f32x4*)qr;
    f32x4 a1 = *(const f32x4*)(qr + 4);
    bf16x8 qa;
#pragma unroll
    for (int j = 0; j < 4; ++j) {
      qa[j] = (__bf16)(a0[j] * QSCALE); qa[j + 4] = (__bf16)(a1[j] * QSCALE);
    }
    qf[c] = qa;
  }

  f32x16 o0, o1;
#pragma unroll
  for (int i = 0; i < 16; ++i) { o0[i] = 0.f; o1[i] = 0.f; }
  float mreg = -1e30f, lsum = 0.f;

  const int swq = (q & 7) << 4;   // XOR swizzle for rows q and q+32 (same &7)

  // ---- staging: 256 threads, 2 units each, held in 32 named VGPRs ----
  const int r_a = tid >> 3, g_a = tid & 7;   // unit a: kv row r_a
  const int r_b = r_a + 32;                  // unit b: kv row r_a+32
  f32x4 sk0a, sk1a, sv0a, sv1a, sk0b, sk1b, sv0b, sv1b;

  auto load_kv = [&](int kv0) {
    const float* ksa = kp + (size_t)(kv0 + r_a) * ROWSTR + g_a * 8;
    const float* vsa = vp + (size_t)(kv0 + r_a) * ROWSTR + g_a * 8;
    sk0a = *(const f32x4*)ksa; sk1a = *(const f32x4*)(ksa + 4);
    sv0a = *(const f32x4*)vsa; sv1a = *(const f32x4*)(vsa + 4);
    const float* ksb = kp + (size_t)(kv0 + r_b) * ROWSTR + g_a * 8;
    const float* vsb = vp + (size_t)(kv0 + r_b) * ROWSTR + g_a * 8;
    sk0b = *(const f32x4*)ksb; sk1b = *(const f32x4*)(ksb + 4);
    sv0b = *(const f32x4*)vsb; sv1b = *(const f32x4*)(vsb + 4);
  };

  auto write_unit = [&](char* kd, char* vd, int r, int g,
                        f32x4 k0, f32x4 k1, f32x4 v0, f32x4 v1) {
    bf16x8 kb;
#pragma unroll
    for (int j = 0; j < 4; ++j) { kb[j] = (__bf16)k0[j]; kb[j + 4] = (__bf16)k1[j]; }
    *(bf16x8*)(kd + ((r * 128 + g * 16) ^ ((r & 7) << 4))) = kb;

    // V^T: pair kv rows (r, r^1) via DPP row_ror:8; even r keeps d 0..3 of
    // its octet, odd r keeps d 4..7; rotate store order by g for bank spread.
    const int odd = r & 1;
    f32x4 tmp = odd ? v0 : v1;
    f32x4 rcv;
#pragma unroll
    for (int j = 0; j < 4; ++j) rcv[j] = dppf<0x128>(tmp[j]);
    const int kvb2 = (r & ~1) * 2;
#pragma unroll
    for (int s = 0; s < 4; ++s) {
      const int dj = (s + g) & 3;
      const float lo = odd ? rcv[dj] : v0[dj];
      const float hi = odd ? v1[dj] : rcv[dj];
      const int d = 8 * g + 4 * odd + dj;
      *(u32*)(vd + ((d * 128 + kvb2) ^ ((d & 7) << 4))) = pack2(lo, hi);
    }
  };
  auto write_kv = [&](char* kd, char* vd) {
    write_unit(kd, vd, r_a, g_a, sk0a, sk1a, sv0a, sv1a);
    write_unit(kd, vd, r_b, g_a, sk0b, sk1b, sv0b, sv1b);
  };

  // ---- prologue: fill buffer 0 ----
  load_kv(0);
  write_kv(k_s[0], v_s[0]);
  __syncthreads();

  int cur = 0;
  for (int t = 0; t <= xhigh; ++t) {
    const int kv0 = t * KVBLK;
    const bool more = (t < xhigh);
    if (more) load_kv(kv0 + KVBLK);   // lands while we compute below

    if (t <= myx) {
      const char* ks = k_s[cur];
      const char* vs = v_s[cur];

      // ---- QK^T (swapped): S^T = K * Q^T ----
      f32x16 p0, p1;
#pragma unroll
      for (int i = 0; i < 16; ++i) { p0[i] = 0.f; p1[i] = 0.f; }
      __builtin_amdgcn_s_setprio(1);
#pragma unroll
      for (int c = 0; c < 4; ++c) {
        const int off = (16 * c + 8 * hh) * 2;
        bf16x8 kf0 = *(const bf16x8*)(ks + ((q * 128 + off) ^ swq));
        bf16x8 kf1 = *(const bf16x8*)(ks + (((32 + q) * 128 + off) ^ swq));
        p0 = __builtin_amdgcn_mfma_f32_32x32x16_bf16(kf0, qf[c], p0, 0, 0, 0);
        p1 = __builtin_amdgcn_mfma_f32_32x32x16_bf16(kf1, qf[c], p1, 0, 0, 0);
      }
      __builtin_amdgcn_s_setprio(0);

      // ---- causal mask (diagonal tile only) ----
      if (t == myx) {
#pragma unroll
        for (int r = 0; r < 16; ++r) {
          const int kvl = (r & 3) + 8 * (r >> 2) + 4 * hh;
          if (kv0 + kvl > myq) p0[r] = -1e30f;
          if (kv0 + 32 + kvl > myq) p1[r] = -1e30f;
        }
      }

      // ---- softmax (per-lane in-register; cross-half via permlane swap) ----
      float tr[16];
#pragma unroll
      for (int i = 0; i < 16; ++i) tr[i] = fmaxf(p0[i], p1[i]);
#pragma unroll
      for (int s = 8; s > 0; s >>= 1)
#pragma unroll
        for (int i = 0; i < 8; ++i)
          if (i < s) tr[i] = fmaxf(tr[i], tr[i + s]);
      float pm = xhalf_max(tr[0]);

      if (__any(pm > mreg + 8.0f)) {
        float mn = fmaxf(mreg, pm);
        float scl = __builtin_exp2f(mreg - mn);
        mreg = mn;
        lsum *= scl;
        o0 *= scl;
        o1 *= scl;
      }

      float s0 = 0.f, s1 = 0.f, s2 = 0.f, s3 = 0.f;
#pragma unroll
      for (int i = 0; i < 16; ++i) {
        p0[i] = __builtin_exp2f(p0[i] - mreg);
        p1[i] = __builtin_exp2f(p1[i] - mreg);
      }
#pragma unroll
      for (int i = 0; i < 4; ++i) {
        s0 += p0[4 * i + 0] + p1[4 * i + 0];
        s1 += p0[4 * i + 1] + p1[4 * i + 1];
        s2 += p0[4 * i + 2] + p1[4 * i + 2];
        s3 += p0[4 * i + 3] + p1[4 * i + 3];
      }
      lsum += (s0 + s1) + (s2 + s3);

      // ---- build P^T B-frags: pack pairs + ONE builtin swap per word pair ----
      // pl32swap(A, B): A <- [own A | partner B] (f low word),
      //                 B <- [partner A | own B] (f high word)   [T12 recipe]
      bf16x8 pb[4];
#pragma unroll
      for (int c = 0; c < 4; ++c) {
        const int m0 = 2 * (c & 1);
        const f32x16& P = (c < 2) ? p0 : p1;
        u32 A0 = pack2(P[4 * m0 + 0], P[4 * m0 + 1]);
        u32 A1 = pack2(P[4 * m0 + 2], P[4 * m0 + 3]);
        u32 B0 = pack2(P[4 * m0 + 4], P[4 * m0 + 5]);
        u32 B1 = pack2(P[4 * m0 + 6], P[4 * m0 + 7]);
        pl32swap(A0, B0);
        pl32swap(A1, B1);
        u32x4 f;
        f[0] = A0;   // j0..1
        f[1] = A1;   // j2..3
        f[2] = B0;   // j4..5
        f[3] = B1;   // j6..7
        pb[c] = __builtin_bit_cast(bf16x8, f);
      }

      // ---- PV: O^T += V^T * P^T ----
      __builtin_amdgcn_s_setprio(1);
#pragma unroll
      for (int c = 0; c < 4; ++c) {
        const int off = (16 * c + 8 * hh) * 2;
        bf16x8 vf0 = *(const bf16x8*)(vs + ((q * 128 + off) ^ swq));
        bf16x8 vf1 = *(const bf16x8*)(vs + (((32 + q) * 128 + off) ^ swq));
        o0 = __builtin_amdgcn_mfma_f32_32x32x16_bf16(vf0, pb[c], o0, 0, 0, 0);
        o1 = __builtin_amdgcn_mfma_f32_32x32x16_bf16(vf1, pb[c], o1, 0, 0, 0);
      }
      __builtin_amdgcn_s_setprio(0);
    }

    if (more) write_kv(k_s[cur ^ 1], v_s[cur ^ 1]);  // vmcnt waits land here
    __syncthreads();   // one barrier: next-buf writes visible + cur-buf reads done
    cur ^= 1;
  }

  // ---- epilogue: combine partner lsum (permlane), normalize, store O^T ----
  lsum = xhalf_sum(lsum);
  const float inv = 1.0f / lsum;
  float* op = out + ((size_t)(b * Sc + myq) * Hc + h) * Dc;
#pragma unroll
  for (int m = 0; m < 4; ++m) {
    f32x4 w0, w1;
#pragma unroll
    for (int j = 0; j < 4; ++j) {
      w0[j] = o0[4 * m + j] * inv;
      w1[j] = o1[4 * m + j] * inv;
    }
    const int d0 = 8 * m + 4 * hh;
    *(f32x4*)(op + d0) = w0;
    *(f32x4*)(op + 32 + d0) = w1;
  }
}

extern "C" void kernel_launch(void* const* d_in, const int* in_sizes, int n_in,
                              void* d_out, int out_size, void* d_ws, size_t ws_size,
                              hipStream_t stream) {
  const float* qkv = (const float*)d_in[0];
  float* out = (float*)d_out;
  dim3 grid(NT / 2, Bc * Hc);   // (16, 32)
  fattn_kernel<<<grid, 256, 0, stream>>>(qkv, out);
}